// Round 1
// baseline (973.432 us; speedup 1.0000x reference)
//
#include <hip/hip_runtime.h>

typedef _Float16 f16x8 __attribute__((ext_vector_type(8)));
typedef float f32x4 __attribute__((ext_vector_type(4)));

#define Bsz 1024
#define Dd  256
#define Hh  1024
#define BM  16
#define ZSTR (Dd + 8)    // 264 fp16 -> 528 B row stride (16B aligned, breaks pow2)
#define ASTR (Hh + 8)    // 1032 fp16 -> 2064 B row stride

// ---------------- prep: transpose + cast fp32 -> fp16 ----------------
// src: R x C fp32 (row-major), dst: C x R fp16 (row-major)
__global__ void transpose_cast_kernel(const float* __restrict__ src,
                                      _Float16* __restrict__ dst,
                                      int R, int C) {
    __shared__ float tile[32][33];
    const int bx = blockIdx.x * 32;   // col base in src
    const int by = blockIdx.y * 32;   // row base in src
    const int x = threadIdx.x;        // 0..31
    const int y0 = threadIdx.y;       // 0..7
#pragma unroll
    for (int i = 0; i < 4; ++i) {
        int y = y0 + i * 8;
        tile[y][x] = src[(by + y) * C + bx + x];
    }
    __syncthreads();
#pragma unroll
    for (int i = 0; i < 4; ++i) {
        int y = y0 + i * 8;
        dst[(bx + y) * R + by + x] = (_Float16)tile[x][y];
    }
}

// ---------------- main: whole RK4 solve, one block = 16 batch rows ----------------
// 64 blocks x 512 threads (8 waves). Wave w owns H-slice [w*128,w*128+128) in
// GEMM1 and D-slice [w*32,w*32+32) in GEMM2. No inter-block communication.
// MFMA 16x16x32 f16 layouts (learn_hip m89/m91/m120):
//   A[m=lane&15][k=(lane>>4)*8+j], B[k=(lane>>4)*8+j][n=lane&15],
//   C/D: col=lane&15, row=(lane>>4)*4+reg.
__global__ __launch_bounds__(512, 2) void ode_kernel(
    const float* __restrict__ z0,
    const float* __restrict__ tv,
    const float* __restrict__ b1,
    const float* __restrict__ b2,
    const _Float16* __restrict__ W1T,   // [Hh][Dd]  (= W1 transposed)
    const _Float16* __restrict__ W2T,   // [Dd][Hh]  (= W2 transposed)
    float* __restrict__ out) {
    __shared__ _Float16 z_lds[BM][ZSTR];     // z_arg, fp16, all waves read
    __shared__ _Float16 act_lds[BM][ASTR];   // tanh activations, fp16

    const int tid  = threadIdx.x;
    const int w    = tid >> 6;        // wave 0..7
    const int lane = tid & 63;
    const int ln   = lane & 15;       // m for A-frags, n for B-frags/C cols
    const int q    = lane >> 4;       // quad 0..3
    const int m0   = blockIdx.x * BM; // batch row base

    const float h = (tv[1] - tv[0]) * 0.125f;   // 8 RK4 steps

    // bias preloads (never change)
    float bb1[8];
#pragma unroll
    for (int nt = 0; nt < 8; ++nt) bb1[nt] = b1[w * 128 + nt * 16 + ln];
    float bb2v[2];
#pragma unroll
    for (int t = 0; t < 2; ++t) bb2v[t] = b2[w * 32 + t * 16 + ln];

    // RK4 state in registers, MFMA C-layout: z[t][r] = z[m0+q*4+r][w*32+t*16+ln]
    f32x4 z[2], zsum[2];
#pragma unroll
    for (int t = 0; t < 2; ++t)
#pragma unroll
        for (int r = 0; r < 4; ++r)
            z[t][r] = z0[(m0 + q * 4 + r) * Dd + w * 32 + t * 16 + ln];

    // initial z_arg -> LDS (each wave writes its D-slice, rows q*4+r)
#pragma unroll
    for (int t = 0; t < 2; ++t)
#pragma unroll
        for (int r = 0; r < 4; ++r)
            z_lds[q * 4 + r][w * 32 + t * 16 + ln] = (_Float16)z[t][r];
    __syncthreads();

#pragma unroll 1
    for (int ev = 0; ev < 32; ++ev) {
        const int e = ev & 3;   // position within RK4 step

        // ---- GEMM1: act[:, w*128..+128) = tanh(z_arg @ W1 + b1) ----
        f16x8 a1[8];            // full K=256 A-fragments, reused across 8 n-tiles
#pragma unroll
        for (int kk = 0; kk < 8; ++kk)
            a1[kk] = *(const f16x8*)&z_lds[ln][kk * 32 + q * 8];

#pragma unroll
        for (int nt = 0; nt < 8; ++nt) {
            const int h0 = w * 128 + nt * 16;
            f32x4 acc = {0.f, 0.f, 0.f, 0.f};
#pragma unroll
            for (int kk = 0; kk < 8; ++kk) {
                f16x8 bf = *(const f16x8*)&W1T[(h0 + ln) * Dd + kk * 32 + q * 8];
                acc = __builtin_amdgcn_mfma_f32_16x16x32_f16(a1[kk], bf, acc, 0, 0, 0);
            }
            // bias + tanh, store to LDS row-major (row = batch, col = h)
#pragma unroll
            for (int r = 0; r < 4; ++r) {
                float x = acc[r] + bb1[nt];
                float ex = __expf(2.0f * x);            // e^{2x}; saturates safely
                float th = 1.0f - 2.0f / (ex + 1.0f);   // tanh(x)
                act_lds[q * 4 + r][h0 + ln] = (_Float16)th;
            }
        }
        __syncthreads();   // act complete; old z_arg now dead

        // ---- GEMM2: k[:, w*32..+32) = act @ W2 + b2 ----
        f32x4 acc2[2] = {{0.f, 0.f, 0.f, 0.f}, {0.f, 0.f, 0.f, 0.f}};
#pragma unroll
        for (int kk = 0; kk < 32; ++kk) {
            f16x8 a2 = *(const f16x8*)&act_lds[ln][kk * 32 + q * 8];
#pragma unroll
            for (int t = 0; t < 2; ++t) {
                const int d0 = w * 32 + t * 16;
                f16x8 bf = *(const f16x8*)&W2T[(d0 + ln) * Hh + kk * 32 + q * 8];
                acc2[t] = __builtin_amdgcn_mfma_f32_16x16x32_f16(a2, bf, acc2[t], 0, 0, 0);
            }
        }

        // ---- RK4 epilogue (fp32, registers only) ----
#pragma unroll
        for (int t = 0; t < 2; ++t) {
            f32x4 k;
#pragma unroll
            for (int r = 0; r < 4; ++r) k[r] = acc2[t][r] + bb2v[t];

            if (e == 0) {
                zsum[t] = k;
            } else if (e == 3) {
#pragma unroll
                for (int r = 0; r < 4; ++r) zsum[t][r] += k[r];
            } else {
#pragma unroll
                for (int r = 0; r < 4; ++r) zsum[t][r] += 2.0f * k[r];
            }

            f32x4 za;
            if (e < 3) {
                const float c = (e == 2) ? h : 0.5f * h;
#pragma unroll
                for (int r = 0; r < 4; ++r) za[r] = z[t][r] + c * k[r];
            } else {
#pragma unroll
                for (int r = 0; r < 4; ++r) {
                    z[t][r] += (h * (1.0f / 6.0f)) * zsum[t][r];
                    za[r] = z[t][r];
                }
            }
            // next z_arg -> LDS (safe: post-barrier, z_lds reads all done)
#pragma unroll
            for (int r = 0; r < 4; ++r)
                z_lds[q * 4 + r][w * 32 + t * 16 + ln] = (_Float16)za[r];
        }
        __syncthreads();   // protects act_lds (next GEMM1 writes) + z_lds reads
    }

    // final z -> out (fp32)
#pragma unroll
    for (int t = 0; t < 2; ++t)
#pragma unroll
        for (int r = 0; r < 4; ++r)
            out[(m0 + q * 4 + r) * Dd + w * 32 + t * 16 + ln] = z[t][r];
}

extern "C" void kernel_launch(void* const* d_in, const int* in_sizes, int n_in,
                              void* d_out, int out_size, void* d_ws, size_t ws_size,
                              hipStream_t stream) {
    const float* z0 = (const float*)d_in[0];
    const float* tv = (const float*)d_in[1];
    const float* W1 = (const float*)d_in[2];   // [256][1024]
    const float* b1 = (const float*)d_in[3];   // [1024]
    const float* W2 = (const float*)d_in[4];   // [1024][256]
    const float* b2 = (const float*)d_in[5];   // [256]
    float* out = (float*)d_out;

    _Float16* W1T = (_Float16*)d_ws;           // [1024][256] fp16, 512 KB
    _Float16* W2T = W1T + Hh * Dd;             // [256][1024] fp16, 512 KB

    dim3 blk(32, 8);
    // W1 (256x1024) -> W1T (1024x256)
    transpose_cast_kernel<<<dim3(Hh / 32, Dd / 32), blk, 0, stream>>>(W1, W1T, Dd, Hh);
    // W2 (1024x256) -> W2T (256x1024)
    transpose_cast_kernel<<<dim3(Dd / 32, Hh / 32), blk, 0, stream>>>(W2, W2T, Hh, Dd);

    ode_kernel<<<64, 512, 0, stream>>>(z0, tv, b1, b2, W1T, W2T, out);
}